// Round 3
// baseline (18.536 us; speedup 1.0000x reference)
//
#include <hip/hip_runtime.h>
#include <hip/hip_bf16.h>

// B=8, C=3, H=512, W=512, K=17. Output = per-pixel max over 16 segments of
// clip(lw+0.5 - dist(pixel,seg), 0, 1), broadcast to 3 channels.
// images' values are unused.
//
// Two-phase: setup kernel bins segments into per-(batch,row,256px-half) masks
// + precomputes segment params; main kernel walks only intersecting segments.

constexpr int BB   = 8;
constexpr int CC   = 3;
constexpr int HH   = 512;
constexpr int WW   = 512;
constexpr int KPTS = 17;
constexpr int NSEG = KPTS - 1;   // 16

constexpr int NMASK = BB * HH * 2;          // 8192 tiles (row x 256px half)
// ws layout: [0, 4096)   params: 8 b x 16 seg x 8 floats {x0,y0,dx,dy,rd,...}
//            [4096, ...) masks : u32[NMASK]
constexpr int PARAM_FLOATS = BB * NSEG * 8;

__global__ __launch_bounds__(256)
void setup_kernel(const float* __restrict__ traj,
                  const int*   __restrict__ lw_p,
                  float*       __restrict__ params,
                  unsigned int* __restrict__ masks)
{
    const int gid = blockIdx.x * 256 + threadIdx.x;
    const float lw = (float)(*lw_p) + 0.5f;

    if (gid < NMASK) {
        const int b    = gid >> 10;          // 1024 tiles per batch
        const int e    = gid & 1023;
        const int row  = e >> 1;
        const int half = e & 1;
        const float fy   = (float)row;
        const float fxlo = (float)(half * 256);
        const float fxhi = fxlo + 255.0f;

        const float* tb = traj + b * (KPTS * 4);
        unsigned int m = 0;
        float xp = tb[1], yp = tb[2];
        #pragma unroll
        for (int s = 0; s < NSEG; ++s) {
            const float xn = tb[s * 4 + 5], yn = tb[s * 4 + 6];
            const float xlo = fminf(xp, xn), xhi = fmaxf(xp, xn);
            const float ylo = fminf(yp, yn), yhi = fmaxf(yp, yn);
            // min dist from tile to segment >= axis gap to bbox
            const bool skip = (ylo - fy   >= lw) | (fy   - yhi >= lw) |
                              (xlo - fxhi >= lw) | (fxlo - xhi >= lw);
            if (!skip) m |= (1u << s);
            xp = xn; yp = yn;
        }
        masks[gid] = m;
    } else if (gid < NMASK + BB * NSEG) {
        const int t = gid - NMASK;
        const int b = t >> 4;
        const int s = t & 15;
        const float* tb = traj + b * (KPTS * 4);
        const float x0 = tb[s * 4 + 1], y0 = tb[s * 4 + 2];
        const float x1 = tb[s * 4 + 5], y1 = tb[s * 4 + 6];
        const float dx = x1 - x0, dy = y1 - y0;
        float* p = params + ((b << 4) + s) * 8;
        p[0] = x0; p[1] = y0; p[2] = dx; p[3] = dy;
        p[4] = __builtin_amdgcn_rcpf(dx * dx + dy * dy + 1e-8f);
    }
}

__global__ __launch_bounds__(256)
void stroke_kernel(const float* __restrict__ params,
                   const unsigned int* __restrict__ masks,
                   const int*   __restrict__ lw_p,
                   float*       __restrict__ out)
{
    // 256 blocks per batch; block = 2 rows. Wave w (of 4): row rb+(w>>1), half w&1.
    const int b   = blockIdx.x >> 8;
    const int rb  = (blockIdx.x & 255) << 1;
    const int tid = threadIdx.x;
    const int wid  = tid >> 6;
    const int row  = rb + (wid >> 1);
    const int half = wid & 1;
    const int lane = tid & 63;
    const int xpx  = half * 256 + lane * 4;

    const float fy  = (float)row;
    const float fx0 = (float)xpx;
    const float lw  = (float)(*lw_p) + 0.5f;

    // wave-uniform mask -> SGPR
    unsigned int m = __builtin_amdgcn_readfirstlane(
        masks[(b << 10) + (row << 1) + half]);

    float acc0 = 0.0f, acc1 = 0.0f, acc2 = 0.0f, acc3 = 0.0f;

    while (m) {
        const int s = __builtin_amdgcn_readfirstlane(__builtin_ctz(m));
        m &= m - 1;
        const float* p = params + ((b << 4) + s) * 8;
        const float x0 = p[0], y0 = p[1], dx = p[2], dy = p[3], rd = p[4];

        const float wy   = fy - y0;
        const float wydy = wy * dy;
        #pragma unroll
        for (int j = 0; j < 4; ++j) {
            const float wx = (fx0 + (float)j) - x0;
            float t = (wx * dx + wydy) * rd;
            t = fminf(fmaxf(t, 0.0f), 1.0f);
            const float ddx  = wx - t * dx;
            const float ddy  = wy - t * dy;
            const float d2   = ddx * ddx + (ddy * ddy + 1e-12f);
            const float dist = __builtin_amdgcn_sqrtf(d2);
            const float cov  = fminf(lw - dist, 1.0f);   // low clamp via acc>=0
            if (j == 0) acc0 = fmaxf(acc0, cov);
            if (j == 1) acc1 = fmaxf(acc1, cov);
            if (j == 2) acc2 = fmaxf(acc2, cov);
            if (j == 3) acc3 = fmaxf(acc3, cov);
        }
    }

    const float4 v = make_float4(acc0, acc1, acc2, acc3);
    const size_t plane = (size_t)HH * WW;
    float* p = out + (size_t)b * CC * plane + (size_t)row * WW + xpx;
    *reinterpret_cast<float4*>(p)             = v;
    *reinterpret_cast<float4*>(p + plane)     = v;
    *reinterpret_cast<float4*>(p + 2 * plane) = v;
}

extern "C" void kernel_launch(void* const* d_in, const int* in_sizes, int n_in,
                              void* d_out, int out_size, void* d_ws, size_t ws_size,
                              hipStream_t stream) {
    const float* traj = (const float*)d_in[1];   // trajectories [8,17,4]
    const int*   lw   = (const int*)d_in[2];     // line_width scalar
    float*       out  = (float*)d_out;           // [8,3,512,512] fp32

    float*        params = (float*)d_ws;
    unsigned int* masks  = (unsigned int*)((char*)d_ws + PARAM_FLOATS * sizeof(float));

    // setup: 8192 mask threads + 128 param threads
    const int setup_threads = NMASK + BB * NSEG;
    setup_kernel<<<(setup_threads + 255) / 256, 256, 0, stream>>>(traj, lw, params, masks);

    stroke_kernel<<<BB * (HH / 2), 256, 0, stream>>>(params, masks, lw, out);
}

// Round 4
// 14.196 us; speedup vs baseline: 1.3057x; 1.3057x over previous
//
#include <hip/hip_runtime.h>
#include <hip/hip_bf16.h>

// B=8, C=3, H=512, W=512, K=17. Output = per-pixel max over 16 segments of
// clip(lw+0.5 - dist(pixel,seg), 0, 1), broadcast to 3 channels.
// images' values are unused.
//
// Single kernel. Per wave (= one row x 256px half-tile): each lane tests
// segment (lane&15) against the tile bbox; __ballot -> wave-uniform 16-bit
// active mask in SGPR; loop over set bits, pulling that segment's params
// from the testing lane via v_readlane (no LDS, no extra dispatch).

constexpr int BB   = 8;
constexpr int CC   = 3;
constexpr int HH   = 512;
constexpr int WW   = 512;
constexpr int KPTS = 17;
constexpr int NSEG = KPTS - 1;   // 16

__device__ __forceinline__ float readlane_f(float v, int lane_sgpr) {
    return __int_as_float(__builtin_amdgcn_readlane(__float_as_int(v), lane_sgpr));
}

__global__ __launch_bounds__(256)
void stroke_kernel(const float* __restrict__ traj,   // [B,K,4] (t,x,y,z)
                   const int*   __restrict__ lw_p,   // scalar line_width
                   float*       __restrict__ out)    // [B,C,H,W]
{
    // 256 blocks/batch; block = 2 rows; wave w: row rb+(w>>1), 256px half (w&1).
    const int b    = blockIdx.x >> 8;
    const int rb   = (blockIdx.x & 255) << 1;
    const int tid  = threadIdx.x;
    const int wid  = tid >> 6;
    const int row  = rb + (wid >> 1);
    const int half = wid & 1;
    const int lane = tid & 63;
    const int xpx  = (half << 8) + (lane << 2);

    const float fy  = (float)row;
    const float fx0 = (float)xpx;
    const float lw  = (float)(*lw_p) + 0.5f;

    // ---- mask phase: lane tests segment (lane & 15) against the wave tile ----
    const int s_l = lane & 15;
    const float* tp = traj + b * (KPTS * 4) + s_l * 4;
    const float x0 = tp[1], y0 = tp[2];
    const float x1 = tp[5], y1 = tp[6];
    const float dx = x1 - x0, dy = y1 - y0;
    const float rd = __builtin_amdgcn_rcpf(dx * dx + dy * dy + 1e-8f);

    const float fxlo = (float)(half << 8);
    const float fxhi = fxlo + 255.0f;
    const float xlo = fminf(x0, x1), xhi = fmaxf(x0, x1);
    const float ylo = fminf(y0, y1), yhi = fmaxf(y0, y1);
    const bool hit = !((ylo - fy   >= lw) | (fy   - yhi >= lw) |
                       (xlo - fxhi >= lw) | (fxlo - xhi >= lw));
    unsigned int m = (unsigned int)__ballot(hit) & 0xFFFFu;
    m = __builtin_amdgcn_readfirstlane(m);

    // ---- eval phase: only intersecting segments ----
    float acc0 = 0.0f, acc1 = 0.0f, acc2 = 0.0f, acc3 = 0.0f;

    while (m) {
        const int s = __builtin_ctz(m);   // SGPR (s_ff1) — m is uniform
        m &= m - 1;
        const float sx0 = readlane_f(x0, s);
        const float sy0 = readlane_f(y0, s);
        const float sdx = readlane_f(dx, s);
        const float sdy = readlane_f(dy, s);
        const float srd = readlane_f(rd, s);

        const float wy   = fy - sy0;
        const float wydy = wy * sdy;
        const float wxb  = fx0 - sx0;

        #pragma unroll
        for (int j = 0; j < 4; ++j) {
            const float wx = wxb + (float)j;
            float t = (wx * sdx + wydy) * srd;
            t = fminf(fmaxf(t, 0.0f), 1.0f);
            const float ddx  = wx - t * sdx;
            const float ddy  = wy - t * sdy;
            const float d2   = ddx * ddx + (ddy * ddy + 1e-12f);
            const float dist = __builtin_amdgcn_sqrtf(d2);
            const float cov  = fminf(lw - dist, 1.0f);   // low clamp via acc>=0
            if (j == 0) acc0 = fmaxf(acc0, cov);
            if (j == 1) acc1 = fmaxf(acc1, cov);
            if (j == 2) acc2 = fmaxf(acc2, cov);
            if (j == 3) acc3 = fmaxf(acc3, cov);
        }
    }

    const float4 v = make_float4(acc0, acc1, acc2, acc3);
    const size_t plane = (size_t)HH * WW;
    float* p = out + (size_t)b * CC * plane + (size_t)row * WW + xpx;
    *reinterpret_cast<float4*>(p)             = v;
    *reinterpret_cast<float4*>(p + plane)     = v;
    *reinterpret_cast<float4*>(p + 2 * plane) = v;
}

extern "C" void kernel_launch(void* const* d_in, const int* in_sizes, int n_in,
                              void* d_out, int out_size, void* d_ws, size_t ws_size,
                              hipStream_t stream) {
    const float* traj = (const float*)d_in[1];   // trajectories [8,17,4]
    const int*   lw   = (const int*)d_in[2];     // line_width scalar
    float*       out  = (float*)d_out;           // [8,3,512,512] fp32

    stroke_kernel<<<BB * (HH / 2), 256, 0, stream>>>(traj, lw, out);
}